// Round 7
// baseline (271.161 us; speedup 1.0000x reference)
//
#include <hip/hip_runtime.h>

// Seq2SeqLSTM: H=64, F=8, T=512, P=64, B=1024, fp32 in/out.
// R19 = R16 champion structure with ONE variable changed: OCCUPANCY.
//   MB 4 -> 2, grid 256 -> 512 blocks = 2 blocks/CU = 2 waves/SIMD.
//   Rationale: R13-R18 ruled out every within-wave resource (MFMA count,
//   LDS BW, bank conflicts, spine algebra) -- the ~670cy step is an exposed
//   latency chain (barrier + ds_read ~120cy + MFMA dep chains + transcendental
//   spine) and at 1 wave/SIMD nothing fills it. Two independent blocks per CU
//   ping-pong: one block's issue fills the other's latency. MFMA work doubles
//   (M=16 tile carries 2 real batches) but the matrix pipe was 71% idle.
//   VGPR 156 <= 256 permits 2 waves/SIMD; LDS 2 x ~21KB fits.
//   Junk lanes (q>=2, no batch) write only never-consumed A-rows 8/12 and
//   scratch predbuf; NaNs there cannot reach real rows (MFMA rows don't mix).
// Structure per block (R16): lane (q,col) owns cell (batch q<MB, unit
// wv*16+col); batch b at A-row 4b so C/D row=4q+0 puts gates in acc[.][0];
// qgates chained pairs g,g,i,i,f,f,o,o; pchain shadow MFMAs in the Qg gap;
// fused-rcp cell with med3 guard; fp16 pre-scaled log2e (2x for g-gate);
// decoder folded W' = Whh + Wih*fcW (pure h-recurrence, pred in shadow).
// REVERTED (measured): R13 swizzle (+7.6us), R14 VALU pdot (+25us), R15
// bundle (+110us), R17 zero-row reads (+4us), R18 px-fold/reg-x (+5.5us).

#define Hh 64
#define Ff 8
#define Tt 512
#define Pp 64
#define BATCH 1024
#define MB 2
#define NBLK (BATCH / MB)   // 512 blocks -> 2 per CU
#define ROWS 72             // halves per A row (64 + 8 pad)
#define ABUF (16 * ROWS + 64)
#define XSTRIDE 16          // halves per x step-row: 2 batches * 8

typedef __attribute__((ext_vector_type(8))) _Float16 half8;
typedef __attribute__((ext_vector_type(4))) _Float16 half4;
typedef __attribute__((ext_vector_type(4))) float f32x4;

#define LOG2E  1.44269504088896340736f
#define K2LOG2 2.88538008177792681472f   // 2*log2e

#define MFMA16(a, b, c) __builtin_amdgcn_mfma_f32_16x16x32_f16(a, b, c, 0, 0, 0)

__device__ __forceinline__ float rcp_(float x)  { return __builtin_amdgcn_rcpf(x); }
__device__ __forceinline__ float exp2_(float x) { return __builtin_amdgcn_exp2f(x); }
// A-row swizzle (halves): rows 4b (writers) keep offset 0.
__device__ __forceinline__ int arow_base(int m) { return m * ROWS + (m & 3) * 16; }

// B-fragments: 4 gate tiles, fp16, log2e-pre-scaled (2*log2e for g-gate).
// B layout (16x16x32): lane holds B[k = kc*32 + q*8 + j][n = col].
__device__ __forceinline__ void load_wfrags(
    const float* __restrict__ Whh, const float* __restrict__ Wih,
    int wv, int q, int col, half8 w0[4], half8 w1[4], half8 wx[4])
{
    #pragma unroll
    for (int Tg = 0; Tg < 4; ++Tg) {
        int g = Tg * 64 + wv * 16 + col;
        float sc = (Tg == 2) ? K2LOG2 : LOG2E;
        const float* r0 = Whh + g * 64 + q * 8;
        #pragma unroll
        for (int j = 0; j < 8; ++j) {
            w0[Tg][j] = (_Float16)(r0[j] * sc);
            w1[Tg][j] = (_Float16)(r0[32 + j] * sc);
            wx[Tg][j] = (q == 0) ? (_Float16)(Wih[g * 8 + j] * sc) : (_Float16)0.f;
        }
    }
}

// P[Tg] = x-contribution + bias (C-init). Off the critical path.
__device__ __forceinline__ void pchain(half8 ax, const half8 wx[4],
                                       const f32x4 biasv[4], f32x4 P[4])
{
    P[2] = MFMA16(ax, wx[2], biasv[2]);
    P[0] = MFMA16(ax, wx[0], biasv[0]);
    P[1] = MFMA16(ax, wx[1], biasv[1]);
    P[3] = MFMA16(ax, wx[3], biasv[3]);
}

// Gate MFMAs: accumulator-chained pairs, g-gate first (longest downstream dep).
__device__ __forceinline__ void qgates(half8 a0, half8 a1,
    const half8 w0[4], const half8 w1[4], const f32x4 P[4], f32x4 Q[4])
{
    Q[2] = MFMA16(a0, w0[2], P[2]);
    Q[2] = MFMA16(a1, w1[2], Q[2]);
    Q[0] = MFMA16(a0, w0[0], P[0]);
    Q[0] = MFMA16(a1, w1[0], Q[0]);
    Q[1] = MFMA16(a0, w0[1], P[1]);
    Q[1] = MFMA16(a1, w1[1], Q[1]);
    Q[3] = MFMA16(a0, w0[3], P[3]);
    Q[3] = MFMA16(a1, w1[3], Q[3]);
}

// Fused-rcp cell. Spine: eg -> it -> cS fma -> med3 -> ec -> rc -> fma -> cvt.
__device__ __forceinline__ float cellf(const f32x4 Q[4], float& cS)
{
    float eg = exp2_(Q[2][0]);            // e^{2g} (g-row pre-scaled 2*log2e)
    float ei = exp2_(-Q[0][0]);
    float it = (eg - 1.f) * rcp_((1.f + ei) * (1.f + eg));   // si*tanh(g)
    float ef = exp2_(-Q[1][0]);
    float sf = rcp_(1.f + ef);
    float eo = exp2_(-Q[3][0]);
    float so   = rcp_(1.f + eo);          // sigmoid(o), off-spine
    float m2so = -2.f * so;
    cS = __builtin_fmaf(sf, cS, K2LOG2 * it);                // cS = 2*log2e*c
    float cc = __builtin_amdgcn_fmed3f(cS, -60.f, 60.f);     // exp2 guard
    float ec = exp2_(cc);                                    // e^{2c}
    float rc = rcp_(1.f + ec);
    return __builtin_fmaf(m2so, rc, so);  // so*tanh(c) = so*(1 - 2/(1+e^{2c}))
}

__global__ __launch_bounds__(256, 2)
void seq2seq_v19(const float* __restrict__ x_seq,
                 const float* __restrict__ eWih, const float* __restrict__ eWhh,
                 const float* __restrict__ ebih, const float* __restrict__ ebhh,
                 const float* __restrict__ dWih, const float* __restrict__ dWhh,
                 const float* __restrict__ dbih, const float* __restrict__ dbhh,
                 const float* __restrict__ fcW,  const float* __restrict__ fcb,
                 float* __restrict__ out)
{
    __shared__ __align__(16) _Float16 xs[(Tt + 2) * XSTRIDE];  // 16.4 KB; predbuf alias
    __shared__ __align__(16) _Float16 A0[ABUF];
    __shared__ __align__(16) _Float16 A1[ABUF];

    const int tid  = threadIdx.x;
    const int wv   = tid >> 6;
    const int lane = tid & 63;
    const int q    = lane >> 4;
    const int col  = lane & 15;
    const int u    = wv * 16 + col;
    const int b0   = blockIdx.x * MB;

    half8 w0[4], w1[4], wx[4];
    load_wfrags(eWhh, eWih, wv, q, col, w0, w1, wx);
    f32x4 biasv[4];
    #pragma unroll
    for (int Tg = 0; Tg < 4; ++Tg) {
        int g = Tg * 64 + u;
        float sc = (Tg == 2) ? K2LOG2 : LOG2E;
        float bv = (ebih[g] + ebhh[g]) * sc;
        biasv[Tg] = (f32x4){bv, bv, bv, bv};
    }

    // init: zero A buffers + xs pad rows, stage x (fp32 -> fp16)
    { int* Z0 = (int*)A0; int* Z1 = (int*)A1;
      for (int i = tid; i < ABUF / 2; i += 256) { Z0[i] = 0; Z1[i] = 0; } }
    if (tid < 16) ((int*)xs)[Tt * (XSTRIDE / 2) + tid] = 0;  // zero 2 pad rows
    for (int i = tid; i < MB * Tt * 2; i += 256) {       // 2048 float4s
        int b   = i >> 10;                               // per-batch: 1024 half4s
        int rem = i & 1023;
        int t   = rem >> 1;
        int f4  = (rem & 1) * 4;
        const float* src = x_seq + ((size_t)(b0 + b) * Tt + t) * Ff + f4;
        half4 s = { (_Float16)src[0], (_Float16)src[1], (_Float16)src[2], (_Float16)src[3] };
        *(half4*)(&xs[t * XSTRIDE + b * 8 + f4]) = s;
    }
    __syncthreads();                                     // staging visible

    // per-lane hoisted pointers (R12/R16 addressing: swizzled A reads via
    // arow_base; writers at rows 4b, swizzle 0).
    const _Float16* arA = A0 + arow_base(col) + q * 8;
    const _Float16* arB = A1 + arow_base(col) + q * 8;
    _Float16* hwA = A0 + 4 * q * ROWS + u;
    _Float16* hwB = A1 + 4 * q * ROWS + u;
    // x walker: real A-rows are 0,4 (batches 0,1) -> batch (col>>2)&1.
    // Junk rows (col=8,12) re-read batch 0/1: in-bounds, outputs never read.
    const _Float16* xq = xs + ((col >> 2) & 1) * 8;

    float cS = 0.f;
    f32x4 P[4];
    {   half8 ax = *(const half8*)(xq);                  // x(0)
        pchain(ax, wx, biasv, P);                        // P for step 0
        xq += XSTRIDE; }

    // ============ encoder: 512 steps, barrier at top, P one step ahead ============
    for (int t = 0; t < Tt; t += 2) {
        __syncthreads();                                 // h(t) visible (A0)
        {
            half8 a0 = *(const half8*)(arA);
            half8 a1 = *(const half8*)(arA + 32);
            half8 ax = *(const half8*)(xq); xq += XSTRIDE;   // x(t+1), off-CP
            f32x4 Q[4];
            qgates(a0, a1, w0, w1, P, Q);
            pchain(ax, wx, biasv, P);                    // fills Qg-latency gap
            float hn = cellf(Q, cS);
            *hwB = (_Float16)hn;                         // h(t+1) -> A1
        }
        __syncthreads();                                 // h(t+1) visible (A1)
        {
            half8 a0 = *(const half8*)(arB);
            half8 a1 = *(const half8*)(arB + 32);
            half8 ax = *(const half8*)(xq); xq += XSTRIDE;   // x(t+2) (pad rows at end)
            f32x4 Q[4];
            qgates(a0, a1, w0, w1, P, Q);
            pchain(ax, wx, biasv, P);
            float hn = cellf(Q, cS);
            *hwA = (_Float16)hn;                         // h(t+2) -> A0
        }
    }
    // after loop: H_0 (encoder final h) in A0.

    // ================= decoder setup =================
    half8 axl = *(const half8*)(xs + (Tt - 1) * XSTRIDE + ((col >> 2) & 1) * 8);

    // Plain decoder weights (step 0 only) + folded weights W' (steps 1..63).
    half8 wp0[4], wp1[4];
    f32x4 biasp[4];
    #pragma unroll
    for (int Tg = 0; Tg < 4; ++Tg) {
        int g = Tg * 64 + u;
        float sc = (Tg == 2) ? K2LOG2 : LOG2E;
        #pragma unroll
        for (int j = 0; j < 8; ++j) {
            int k0 = q * 8 + j;
            float v0 = dWhh[g * 64 + k0];
            float v1 = dWhh[g * 64 + 32 + k0];
            w0[Tg][j] = (_Float16)(v0 * sc);             // plain (step 0)
            w1[Tg][j] = (_Float16)(v1 * sc);
            wx[Tg][j] = (q == 0) ? (_Float16)(dWih[g * 8 + j] * sc) : (_Float16)0.f;
            float s0 = v0, s1 = v1;                      // fold: W' = Whh + Wih*fcW
            #pragma unroll
            for (int f = 0; f < 8; ++f) {
                float wif = dWih[g * 8 + f];
                s0 = __builtin_fmaf(wif, fcW[f * 64 + k0], s0);
                s1 = __builtin_fmaf(wif, fcW[f * 64 + 32 + k0], s1);
            }
            wp0[Tg][j] = (_Float16)(s0 * sc);
            wp1[Tg][j] = (_Float16)(s1 * sc);
        }
        float bb = dbih[g] + dbhh[g];
        float bp = bb;                                   // b' = b + Wih*fcb
        #pragma unroll
        for (int f = 0; f < 8; ++f) bp = __builtin_fmaf(dWih[g * 8 + f], fcb[f], bp);
        biasv[Tg] = (f32x4){bb * sc, bb * sc, bb * sc, bb * sc};
        biasp[Tg] = (f32x4){bp * sc, bp * sc, bp * sc, bp * sc};
    }
    // fc fragments: pred[b][f] = sum_u h[b][u]*fcW[f][u] + fcb[f]
    half8 wf0, wf1;
    f32x4 biasf;
    {
        #pragma unroll
        for (int j = 0; j < 8; ++j) {
            wf0[j] = (col < 8) ? (_Float16)fcW[col * 64 + q * 8 + j]      : (_Float16)0.f;
            wf1[j] = (col < 8) ? (_Float16)fcW[col * 64 + 32 + q * 8 + j] : (_Float16)0.f;
        }
        float fb = (col < 8) ? fcb[col] : 0.f;
        biasf = (f32x4){fb, fb, fb, fb};
    }

    float* predbuf = (float*)xs;                         // alias over dead xs
    const bool pw = (wv == 0) && (col < 8);              // pred writer lanes
                                                         // (q>=MB -> scratch, harmless)

    // ---- decoder step 0: plain path, x = x_last; pchain hoisted off-CP ----
    pchain(axl, wx, biasv, P);
    __syncthreads();                                     // H_0 visible (A0)
    {
        half8 a0 = *(const half8*)(arA);
        half8 a1 = *(const half8*)(arA + 32);
        f32x4 Q[4];
        qgates(a0, a1, w0, w1, P, Q);
        float hn = cellf(Q, cS);
        *hwB = (_Float16)hn;                             // H_1 -> A1
    }

    // ---- decoder steps 1..63: pure h-recurrence (folded W'), pred in shadow ----
    for (int p = 1; p < Pp; ++p) {
        __syncthreads();                                 // H_p visible
        const _Float16* ar = (p & 1) ? arB : arA;
        _Float16*       hw = (p & 1) ? hwA : hwB;
        half8 a0 = *(const half8*)(ar);
        half8 a1 = *(const half8*)(ar + 32);
        f32x4 Q[4];
        qgates(a0, a1, wp0, wp1, biasp, Q);              // CP: same as encoder
        // shadow: pred(p-1) = fc(H_p), issued into the Qg-latency gap
        f32x4 F = MFMA16(a0, wf0, biasf);
        F       = MFMA16(a1, wf1, F);
        float hn = cellf(Q, cS);
        *hw = (_Float16)hn;                              // H_{p+1}
        if (pw) predbuf[q * (Pp * Ff) + (p - 1) * Ff + col] = F[0];
    }

    // ---- epilogue: pred(63) = fc(H_64) (H_64 in A0: p=63 odd wrote hwA) ----
    __syncthreads();
    {
        half8 a0 = *(const half8*)(arA);
        half8 a1 = *(const half8*)(arA + 32);
        f32x4 F = MFMA16(a0, wf0, biasf);
        F       = MFMA16(a1, wf1, F);
        if (pw) predbuf[q * (Pp * Ff) + (Pp - 1) * Ff + col] = F[0];
    }
    __syncthreads();

    // ================= flush preds: LDS -> global, coalesced float4 =================
    {
        f32x4* out4 = (f32x4*)out + (size_t)b0 * (Pp * Ff / 4);
        const f32x4* pb4 = (const f32x4*)predbuf;
        for (int i = tid; i < MB * Pp * Ff / 4; i += 256)
            out4[i] = pb4[i];
    }
}

extern "C" void kernel_launch(void* const* d_in, const int* in_sizes, int n_in,
                              void* d_out, int out_size, void* d_ws, size_t ws_size,
                              hipStream_t stream) {
    (void)in_sizes; (void)n_in; (void)d_ws; (void)ws_size; (void)out_size;
    hipLaunchKernelGGL(seq2seq_v19, dim3(NBLK), dim3(256), 0, stream,
                       (const float*)d_in[0],
                       (const float*)d_in[1], (const float*)d_in[2],
                       (const float*)d_in[3], (const float*)d_in[4],
                       (const float*)d_in[5], (const float*)d_in[6],
                       (const float*)d_in[7], (const float*)d_in[8],
                       (const float*)d_in[9], (const float*)d_in[10],
                       (float*)d_out);
}

// Round 8
// 248.703 us; speedup vs baseline: 1.0903x; 1.0903x over previous
//
#include <hip/hip_runtime.h>

// Seq2SeqLSTM: H=64, F=8, T=512, P=64, B=1024, fp32 in/out.
// R20 = R16 champion + ONE isolated change: SPLIT-K GATE MFMAs.
//   Each gate was 2 accumulator-chained MFMAs (Q-ready = 2x MFMA dep
//   latency after a0/a1). Now: QA = mfma(a0,w0,P) and QB = mfma(a1,w1,0)
//   are INDEPENDENT (issue back-to-back, complete in parallel); gate =
//   QA[0]+QB[0] (one VALU add at the spine head). Q-ready = 1x latency +
//   4cy -> ~25-35cy off the h-loop critical path. Cost: +16 VGPR (no
//   occupancy change at 1 wave/SIMD), 4 spine-head adds.
//   This isolates R15's item (2), which was bundled with the ROWS=68
//   alignment poison there. ROWS stays 72; addressing identical to R16.
// Occupancy ledger (R19): MB=2 @ 2 blocks/CU -> Occ 21%, MfmaUtil 43%,
//   but +42% wall: halving MB doubles per-batch MFMA work (M-tile waste).
//   MB=4 x 256 blocks is the matched decomposition. REVERTED.
// Structure (R16): lane (q,col) owns cell (batch q, unit wv*16+col); batch
// b at A-row 4b so C/D row=4q+0 puts gates in acc[.][0]; pchain shadow
// MFMAs after qgates; fused-rcp cell with med3 guard; fp16 pre-scaled
// log2e (2x for g-gate); decoder folded W' = Whh + Wih*fcW.
// REVERTED (measured): R13 swizzle (+7.6us), R14 VALU pdot (+25us), R15
// bundle (+110us), R17 zero-row reads (+4us), R18 px-fold (+5.5us),
// R19 occupancy (+67us).

#define Hh 64
#define Ff 8
#define Tt 512
#define Pp 64
#define BATCH 1024
#define MB 4
#define NBLK (BATCH / MB)   // 256 blocks
#define ROWS 72             // halves per A row (64 + 8 pad)
#define ABUF (16 * ROWS + 64)
#define XSTRIDE 32          // halves per x step-row: 4 batches * 8

typedef __attribute__((ext_vector_type(8))) _Float16 half8;
typedef __attribute__((ext_vector_type(4))) _Float16 half4;
typedef __attribute__((ext_vector_type(4))) float f32x4;

#define LOG2E  1.44269504088896340736f
#define K2LOG2 2.88538008177792681472f   // 2*log2e

#define MFMA16(a, b, c) __builtin_amdgcn_mfma_f32_16x16x32_f16(a, b, c, 0, 0, 0)

__device__ __forceinline__ float rcp_(float x)  { return __builtin_amdgcn_rcpf(x); }
__device__ __forceinline__ float exp2_(float x) { return __builtin_amdgcn_exp2f(x); }
// A-row swizzle (halves): rows 4b (writers) keep offset 0.
__device__ __forceinline__ int arow_base(int m) { return m * ROWS + (m & 3) * 16; }

// B-fragments: 4 gate tiles, fp16, log2e-pre-scaled (2*log2e for g-gate).
// B layout (16x16x32): lane holds B[k = kc*32 + q*8 + j][n = col].
__device__ __forceinline__ void load_wfrags(
    const float* __restrict__ Whh, const float* __restrict__ Wih,
    int wv, int q, int col, half8 w0[4], half8 w1[4], half8 wx[4])
{
    #pragma unroll
    for (int Tg = 0; Tg < 4; ++Tg) {
        int g = Tg * 64 + wv * 16 + col;
        float sc = (Tg == 2) ? K2LOG2 : LOG2E;
        const float* r0 = Whh + g * 64 + q * 8;
        #pragma unroll
        for (int j = 0; j < 8; ++j) {
            w0[Tg][j] = (_Float16)(r0[j] * sc);
            w1[Tg][j] = (_Float16)(r0[32 + j] * sc);
            wx[Tg][j] = (q == 0) ? (_Float16)(Wih[g * 8 + j] * sc) : (_Float16)0.f;
        }
    }
}

// P[Tg] = x-contribution + bias (C-init). Off the critical path.
__device__ __forceinline__ void pchain(half8 ax, const half8 wx[4],
                                       const f32x4 biasv[4], f32x4 P[4])
{
    P[2] = MFMA16(ax, wx[2], biasv[2]);
    P[0] = MFMA16(ax, wx[0], biasv[0]);
    P[1] = MFMA16(ax, wx[1], biasv[1]);
    P[3] = MFMA16(ax, wx[3], biasv[3]);
}

// Gate MFMAs: SPLIT-K -- two independent halves per gate, g-gate first.
// QA C-init carries P (x+bias); QB C-init is zero. gate = QA[0]+QB[0].
__device__ __forceinline__ void qgates2(half8 a0, half8 a1,
    const half8 w0[4], const half8 w1[4], const f32x4 P[4], f32x4 Z,
    f32x4 QA[4], f32x4 QB[4])
{
    QA[2] = MFMA16(a0, w0[2], P[2]);
    QB[2] = MFMA16(a1, w1[2], Z);
    QA[0] = MFMA16(a0, w0[0], P[0]);
    QB[0] = MFMA16(a1, w1[0], Z);
    QA[1] = MFMA16(a0, w0[1], P[1]);
    QB[1] = MFMA16(a1, w1[1], Z);
    QA[3] = MFMA16(a0, w0[3], P[3]);
    QB[3] = MFMA16(a1, w1[3], Z);
}

// Fused-rcp cell, split-K heads. Spine: add -> eg -> it -> cS fma -> med3
// -> ec -> rc -> fma -> cvt.
__device__ __forceinline__ float cellf2(const f32x4 QA[4], const f32x4 QB[4],
                                        float& cS)
{
    float eg = exp2_(QA[2][0] + QB[2][0]);   // e^{2g} (g pre-scaled 2*log2e)
    float ei = exp2_(-(QA[0][0] + QB[0][0]));
    float it = (eg - 1.f) * rcp_((1.f + ei) * (1.f + eg));   // si*tanh(g)
    float ef = exp2_(-(QA[1][0] + QB[1][0]));
    float sf = rcp_(1.f + ef);
    float eo = exp2_(-(QA[3][0] + QB[3][0]));
    float so   = rcp_(1.f + eo);          // sigmoid(o), off-spine
    float m2so = -2.f * so;
    cS = __builtin_fmaf(sf, cS, K2LOG2 * it);                // cS = 2*log2e*c
    float cc = __builtin_amdgcn_fmed3f(cS, -60.f, 60.f);     // exp2 guard
    float ec = exp2_(cc);                                    // e^{2c}
    float rc = rcp_(1.f + ec);
    return __builtin_fmaf(m2so, rc, so);  // so*tanh(c) = so*(1 - 2/(1+e^{2c}))
}

__global__ __launch_bounds__(256, 1)
void seq2seq_v20(const float* __restrict__ x_seq,
                 const float* __restrict__ eWih, const float* __restrict__ eWhh,
                 const float* __restrict__ ebih, const float* __restrict__ ebhh,
                 const float* __restrict__ dWih, const float* __restrict__ dWhh,
                 const float* __restrict__ dbih, const float* __restrict__ dbhh,
                 const float* __restrict__ fcW,  const float* __restrict__ fcb,
                 float* __restrict__ out)
{
    __shared__ __align__(16) _Float16 xs[(Tt + 2) * XSTRIDE];  // 32.9 KB; predbuf alias
    __shared__ __align__(16) _Float16 A0[ABUF];
    __shared__ __align__(16) _Float16 A1[ABUF];

    const int tid  = threadIdx.x;
    const int wv   = tid >> 6;
    const int lane = tid & 63;
    const int q    = lane >> 4;
    const int col  = lane & 15;
    const int u    = wv * 16 + col;
    const int b0   = blockIdx.x * MB;
    const f32x4 Zv = {0.f, 0.f, 0.f, 0.f};

    half8 w0[4], w1[4], wx[4];
    load_wfrags(eWhh, eWih, wv, q, col, w0, w1, wx);
    f32x4 biasv[4];
    #pragma unroll
    for (int Tg = 0; Tg < 4; ++Tg) {
        int g = Tg * 64 + u;
        float sc = (Tg == 2) ? K2LOG2 : LOG2E;
        float bv = (ebih[g] + ebhh[g]) * sc;
        biasv[Tg] = (f32x4){bv, bv, bv, bv};
    }

    // init: zero A buffers + xs pad rows, stage x (fp32 -> fp16)
    { int* Z0 = (int*)A0; int* Z1 = (int*)A1;
      for (int i = tid; i < ABUF / 2; i += 256) { Z0[i] = 0; Z1[i] = 0; } }
    if (tid < 32) ((int*)xs)[Tt * 16 + tid] = 0;         // zero 2 pad rows
    for (int i = tid; i < MB * Tt * 2; i += 256) {       // 4096 float4s
        int b   = i >> 10;
        int rem = i & 1023;
        int t   = rem >> 1;
        int f4  = (rem & 1) * 4;
        const float* src = x_seq + ((size_t)(b0 + b) * Tt + t) * Ff + f4;
        half4 s = { (_Float16)src[0], (_Float16)src[1], (_Float16)src[2], (_Float16)src[3] };
        *(half4*)(&xs[t * XSTRIDE + b * 8 + f4]) = s;
    }
    __syncthreads();                                     // staging visible

    // per-lane hoisted pointers (R12/R16 addressing: swizzled A reads via
    // arow_base; writers at rows 4b, swizzle 0).
    const _Float16* arA = A0 + arow_base(col) + q * 8;
    const _Float16* arB = A1 + arow_base(col) + q * 8;
    _Float16* hwA = A0 + 4 * q * ROWS + u;
    _Float16* hwB = A1 + 4 * q * ROWS + u;
    const _Float16* xq = xs + (col >> 2) * 8;            // x walker (broadcast groups)

    float cS = 0.f;
    f32x4 P[4];
    {   half8 ax = *(const half8*)(xq);                  // x(0)
        pchain(ax, wx, biasv, P);                        // P for step 0
        xq += XSTRIDE; }

    // ============ encoder: 512 steps, barrier at top, P one step ahead ============
    for (int t = 0; t < Tt; t += 2) {
        __syncthreads();                                 // h(t) visible (A0)
        {
            half8 a0 = *(const half8*)(arA);
            half8 a1 = *(const half8*)(arA + 32);
            half8 ax = *(const half8*)(xq); xq += XSTRIDE;   // x(t+1), off-CP
            f32x4 QA[4], QB[4];
            qgates2(a0, a1, w0, w1, P, Zv, QA, QB);
            pchain(ax, wx, biasv, P);                    // shadow, fills latency gap
            float hn = cellf2(QA, QB, cS);
            *hwB = (_Float16)hn;                         // h(t+1) -> A1
        }
        __syncthreads();                                 // h(t+1) visible (A1)
        {
            half8 a0 = *(const half8*)(arB);
            half8 a1 = *(const half8*)(arB + 32);
            half8 ax = *(const half8*)(xq); xq += XSTRIDE;   // x(t+2) (pad rows at end)
            f32x4 QA[4], QB[4];
            qgates2(a0, a1, w0, w1, P, Zv, QA, QB);
            pchain(ax, wx, biasv, P);
            float hn = cellf2(QA, QB, cS);
            *hwA = (_Float16)hn;                         // h(t+2) -> A0
        }
    }
    // after loop: H_0 (encoder final h) in A0.

    // ================= decoder setup =================
    half8 axl = *(const half8*)(xs + (Tt - 1) * XSTRIDE + (col >> 2) * 8);

    // Plain decoder weights (step 0 only) + folded weights W' (steps 1..63).
    half8 wp0[4], wp1[4];
    f32x4 biasp[4];
    #pragma unroll
    for (int Tg = 0; Tg < 4; ++Tg) {
        int g = Tg * 64 + u;
        float sc = (Tg == 2) ? K2LOG2 : LOG2E;
        #pragma unroll
        for (int j = 0; j < 8; ++j) {
            int k0 = q * 8 + j;
            float v0 = dWhh[g * 64 + k0];
            float v1 = dWhh[g * 64 + 32 + k0];
            w0[Tg][j] = (_Float16)(v0 * sc);             // plain (step 0)
            w1[Tg][j] = (_Float16)(v1 * sc);
            wx[Tg][j] = (q == 0) ? (_Float16)(dWih[g * 8 + j] * sc) : (_Float16)0.f;
            float s0 = v0, s1 = v1;                      // fold: W' = Whh + Wih*fcW
            #pragma unroll
            for (int f = 0; f < 8; ++f) {
                float wif = dWih[g * 8 + f];
                s0 = __builtin_fmaf(wif, fcW[f * 64 + k0], s0);
                s1 = __builtin_fmaf(wif, fcW[f * 64 + 32 + k0], s1);
            }
            wp0[Tg][j] = (_Float16)(s0 * sc);
            wp1[Tg][j] = (_Float16)(s1 * sc);
        }
        float bb = dbih[g] + dbhh[g];
        float bp = bb;                                   // b' = b + Wih*fcb
        #pragma unroll
        for (int f = 0; f < 8; ++f) bp = __builtin_fmaf(dWih[g * 8 + f], fcb[f], bp);
        biasv[Tg] = (f32x4){bb * sc, bb * sc, bb * sc, bb * sc};
        biasp[Tg] = (f32x4){bp * sc, bp * sc, bp * sc, bp * sc};
    }
    // fc fragments: pred[b][f] = sum_u h[b][u]*fcW[f][u] + fcb[f]
    half8 wf0, wf1;
    f32x4 biasf;
    {
        #pragma unroll
        for (int j = 0; j < 8; ++j) {
            wf0[j] = (col < 8) ? (_Float16)fcW[col * 64 + q * 8 + j]      : (_Float16)0.f;
            wf1[j] = (col < 8) ? (_Float16)fcW[col * 64 + 32 + q * 8 + j] : (_Float16)0.f;
        }
        float fb = (col < 8) ? fcb[col] : 0.f;
        biasf = (f32x4){fb, fb, fb, fb};
    }

    float* predbuf = (float*)xs;                         // 8 KB alias over dead xs
    const bool pw = (wv == 0) && (col < 8);              // pred writer lanes

    // ---- decoder step 0: plain path, x = x_last; pchain hoisted off-CP ----
    pchain(axl, wx, biasv, P);
    __syncthreads();                                     // H_0 visible (A0)
    {
        half8 a0 = *(const half8*)(arA);
        half8 a1 = *(const half8*)(arA + 32);
        f32x4 QA[4], QB[4];
        qgates2(a0, a1, w0, w1, P, Zv, QA, QB);
        float hn = cellf2(QA, QB, cS);
        *hwB = (_Float16)hn;                             // H_1 -> A1
    }

    // ---- decoder steps 1..63: pure h-recurrence (folded W'), pred in shadow ----
    for (int p = 1; p < Pp; ++p) {
        __syncthreads();                                 // H_p visible
        const _Float16* ar = (p & 1) ? arB : arA;
        _Float16*       hw = (p & 1) ? hwA : hwB;
        half8 a0 = *(const half8*)(ar);
        half8 a1 = *(const half8*)(ar + 32);
        f32x4 QA[4], QB[4];
        qgates2(a0, a1, wp0, wp1, biasp, Zv, QA, QB);    // CP: same as encoder
        // shadow: pred(p-1) = fc(H_p), issued into the latency gap
        f32x4 F = MFMA16(a0, wf0, biasf);
        F       = MFMA16(a1, wf1, F);
        float hn = cellf2(QA, QB, cS);
        *hw = (_Float16)hn;                              // H_{p+1}
        if (pw) predbuf[q * (Pp * Ff) + (p - 1) * Ff + col] = F[0];
    }

    // ---- epilogue: pred(63) = fc(H_64) (H_64 in A0: p=63 odd wrote hwA) ----
    __syncthreads();
    {
        half8 a0 = *(const half8*)(arA);
        half8 a1 = *(const half8*)(arA + 32);
        f32x4 F = MFMA16(a0, wf0, biasf);
        F       = MFMA16(a1, wf1, F);
        if (pw) predbuf[q * (Pp * Ff) + (Pp - 1) * Ff + col] = F[0];
    }
    __syncthreads();

    // ================= flush preds: LDS -> global, coalesced float4 =================
    {
        f32x4* out4 = (f32x4*)out + (size_t)b0 * (Pp * Ff / 4);
        const f32x4* pb4 = (const f32x4*)predbuf;
        for (int i = tid; i < MB * Pp * Ff / 4; i += 256)
            out4[i] = pb4[i];
    }
}

extern "C" void kernel_launch(void* const* d_in, const int* in_sizes, int n_in,
                              void* d_out, int out_size, void* d_ws, size_t ws_size,
                              hipStream_t stream) {
    (void)in_sizes; (void)n_in; (void)d_ws; (void)ws_size; (void)out_size;
    hipLaunchKernelGGL(seq2seq_v20, dim3(NBLK), dim3(256), 0, stream,
                       (const float*)d_in[0],
                       (const float*)d_in[1], (const float*)d_in[2],
                       (const float*)d_in[3], (const float*)d_in[4],
                       (const float*)d_in[5], (const float*)d_in[6],
                       (const float*)d_in[7], (const float*)d_in[8],
                       (const float*)d_in[9], (const float*)d_in[10],
                       (float*)d_out);
}